// Round 5
// baseline (209.585 us; speedup 1.0000x reference)
//
#include <hip/hip_runtime.h>
#include <hip/hip_bf16.h>

typedef __attribute__((ext_vector_type(8))) short short8;
typedef __attribute__((ext_vector_type(4))) float f32x4;

#define HSZ 128
#define BM  64
#define NT  512

__device__ __forceinline__ unsigned short f2bf(float f) {
    union { float f; unsigned int u; } c; c.f = f;
    return (unsigned short)((c.u + 0x7FFFu + ((c.u >> 16) & 1u)) >> 16);
}

// Pack W (bf16) as Wp[col][k] (k contiguous, 16B-aligned fragments).
// W[k][g*128+i] = ih[g*128+k][i] (k<128) else hh[g*128+(k-128)][i].
__global__ void prep_kernel(const float* __restrict__ ih, const float* __restrict__ hh,
                            const float* __restrict__ ib, const float* __restrict__ hb,
                            unsigned short* __restrict__ Wp, float* __restrict__ bias) {
    int tid = blockIdx.x * blockDim.x + threadIdx.x;   // 0..16383
    int col = tid >> 5;                                // 0..511
    int kg  = tid & 31;                                // 0..31
    int g = col >> 7, i = col & 127;
    short8 pk;
    #pragma unroll
    for (int j = 0; j < 8; ++j) {
        int k = kg * 8 + j;
        float v = (k < HSZ) ? ih[(g * HSZ + k) * HSZ + i]
                            : hh[(g * HSZ + (k - HSZ)) * HSZ + i];
        pk[j] = (short)f2bf(v);
    }
    *reinterpret_cast<short8*>(Wp + col * 256 + kg * 8) = pk;
    if (kg == 0) bias[col] = ib[col] + hb[col];
}

union SMem {
    unsigned short A[BM * 264];   // 33792 B bf16 activations (dead after MFMA)
    float T[8][2048];             // per-wave 8 KB: 2 slots x 1024 f32 (32x32 tile)
};

__global__ __launch_bounds__(NT, 4)   // 2 blocks/CU
void lstm_kernel(const float* __restrict__ x, const float* __restrict__ h0,
                 const float* __restrict__ c0,
                 const unsigned short* __restrict__ Wp,
                 const float* __restrict__ biasp,
                 float* __restrict__ out, long BH) {
    constexpr int PITCH = 264;
    __shared__ SMem sm;

    const int t = threadIdx.x;
    const long rowBase = (long)blockIdx.x * BM;

    // ---- stage A = [x | h0] (64 rows x 256 k) as bf16 into LDS ----
    {
        const float4* x4 = reinterpret_cast<const float4*>(x + rowBase * HSZ);
        const float4* h4 = reinterpret_cast<const float4*>(h0 + rowBase * HSZ);
        #pragma unroll
        for (int j = 0; j < 4; ++j) {
            int fi = t + j * NT;               // 0..2047
            int row = fi >> 5;
            int c4  = fi & 31;
            float4 vx = x4[fi];
            float4 vh = h4[fi];
            ushort4 px; px.x = f2bf(vx.x); px.y = f2bf(vx.y); px.z = f2bf(vx.z); px.w = f2bf(vx.w);
            ushort4 ph; ph.x = f2bf(vh.x); ph.y = f2bf(vh.y); ph.z = f2bf(vh.z); ph.w = f2bf(vh.w);
            *reinterpret_cast<ushort4*>(&sm.A[row * PITCH + c4 * 4]) = px;
            *reinterpret_cast<ushort4*>(&sm.A[row * PITCH + HSZ + c4 * 4]) = ph;
        }
    }
    __syncthreads();

    const int lane = t & 63;
    const int wid  = t >> 6;
    const int wm = wid & 1;            // row half (32 rows)
    const int wn = wid >> 1;           // 0..3: intra-gate col quarter (32 cols)
    const int lr = lane & 15;
    const int lk = lane >> 4;          // k-group (8 bf16)

    const char* Ab = reinterpret_cast<const char*>(sm.A)
                   + (wm * 32 + lr) * (PITCH * 2) + lk * 16;
    const char* Wb = reinterpret_cast<const char*>(Wp)
                   + (wn * 32 + lr) * 512 + lk * 16;

    f32x4 acc[2][2][4] = {};   // [mi][ni][gate]

    #pragma unroll
    for (int ks = 0; ks < 8; ++ks) {
        short8 a0 = *reinterpret_cast<const short8*>(Ab + ks * 64);
        short8 a1 = *reinterpret_cast<const short8*>(Ab + 16 * (PITCH * 2) + ks * 64);
        #pragma unroll
        for (int g = 0; g < 4; ++g) {
            #pragma unroll
            for (int ni = 0; ni < 2; ++ni) {
                short8 w = *reinterpret_cast<const short8*>(
                    Wb + (g * 128 + ni * 16) * 512 + ks * 64);
                // Swapped operands: lane's 4 acc regs = 4 consecutive gate cols
                acc[0][ni][g] = __builtin_amdgcn_mfma_f32_16x16x32_bf16(w, a0, acc[0][ni][g], 0, 0, 0);
                acc[1][ni][g] = __builtin_amdgcn_mfma_f32_16x16x32_bf16(w, a1, acc[1][ni][g], 0, 0, 0);
            }
        }
    }

    // ---- c0 load (latency hidden by bias fold + barrier) ----
    f32x4 c0v[2][2];
    #pragma unroll
    for (int mi = 0; mi < 2; ++mi)
        #pragma unroll
        for (int ni = 0; ni < 2; ++ni) {
            long pos = (rowBase + wm * 32 + mi * 16 + lr) * HSZ
                     + wn * 32 + ni * 16 + lk * 4;
            c0v[mi][ni] = *reinterpret_cast<const f32x4*>(c0 + pos);
        }

    // ---- fold bias into acc ----
    #pragma unroll
    for (int ni = 0; ni < 2; ++ni)
        #pragma unroll
        for (int g = 0; g < 4; ++g) {
            f32x4 bg = *reinterpret_cast<const f32x4*>(
                biasp + g * HSZ + wn * 32 + ni * 16 + lk * 4);
            acc[0][ni][g] += bg;
            acc[1][ni][g] += bg;
        }

    __syncthreads();   // A tile dead; LDS becomes per-wave transpose slots.
                       // Last block-wide barrier — epilogue is 100% wave-local.

    float* wt = sm.T[wid];             // this wave's 2 slots (2 x 1024 f32)
    const long rbase = (rowBase + wm * 32) * (long)HSZ + wn * 32;
    const int rr0 = lane >> 3;         // read-back: row within 8-row group
    const int gg0 = lane & 7;          // read-back: granule (16B) within line

    // ---- c_1 -> slot0, h_1 -> slot1 (per-fragment, transient regs) ----
    #pragma unroll
    for (int mi = 0; mi < 2; ++mi)
        #pragma unroll
        for (int ni = 0; ni < 2; ++ni) {
            int row = mi * 16 + lr;
            int g4  = ni * 4 + lk;                       // granule col index 0..7
            f32x4 c1v, h1v;
            #pragma unroll
            for (int r = 0; r < 4; ++r) {
                float iv = acc[mi][ni][0][r];
                float fv = acc[mi][ni][1][r];
                float gv = acc[mi][ni][2][r];
                float ov = acc[mi][ni][3][r];
                float si = 1.f / (1.f + __expf(-iv));
                float sf = 1.f / (1.f + __expf(-fv));
                float tg = 1.f - 2.f / (__expf(2.f * gv) + 1.f);
                float so = 1.f / (1.f + __expf(-ov));
                float c1 = c0v[mi][ni][r] * sf + si * tg;
                float th = 1.f - 2.f / (__expf(2.f * c1) + 1.f);
                c1v[r] = c1;
                h1v[r] = so + th;
            }
            int idx = row * 32 + ((g4 ^ (row & 7)) * 4); // XOR-swizzled granule
            *reinterpret_cast<f32x4*>(&wt[idx])        = c1v;
            *reinterpret_cast<f32x4*>(&wt[1024 + idx]) = h1v;
        }
    __builtin_amdgcn_wave_barrier();

    // ---- flush c_1 (slot0) and h_1 (slot1): full 128B-line nt stores ----
    #pragma unroll
    for (int p = 0; p < 4; ++p) {
        int rr  = p * 8 + rr0;
        int idx = rr * 32 + ((gg0 ^ (rr & 7)) * 4);
        f32x4 vc = *reinterpret_cast<const f32x4*>(&wt[idx]);
        f32x4 vh = *reinterpret_cast<const f32x4*>(&wt[1024 + idx]);
        long rpos = rbase + (long)rr * HSZ + gg0 * 4;
        __builtin_nontemporal_store(vc, reinterpret_cast<f32x4*>(out + BH + rpos));
        __builtin_nontemporal_store(vh, reinterpret_cast<f32x4*>(out + rpos));
    }
    __builtin_amdgcn_wave_barrier();

    // ---- raw gates I, F, G, O via ping-pong slots ----
    #pragma unroll
    for (int g = 0; g < 4; ++g) {
        float* slot = wt + (g & 1) * 1024;
        #pragma unroll
        for (int mi = 0; mi < 2; ++mi)
            #pragma unroll
            for (int ni = 0; ni < 2; ++ni) {
                int row = mi * 16 + lr;
                int g4  = ni * 4 + lk;
                int idx = row * 32 + ((g4 ^ (row & 7)) * 4);
                *reinterpret_cast<f32x4*>(&slot[idx]) = acc[mi][ni][g];
            }
        __builtin_amdgcn_wave_barrier();
        #pragma unroll
        for (int p = 0; p < 4; ++p) {
            int rr  = p * 8 + rr0;
            int idx = rr * 32 + ((gg0 ^ (rr & 7)) * 4);
            f32x4 v = *reinterpret_cast<const f32x4*>(&slot[idx]);
            long rpos = rbase + (long)rr * HSZ + gg0 * 4;
            __builtin_nontemporal_store(v,
                reinterpret_cast<f32x4*>(out + (long)(2 + g) * BH + rpos));
        }
        __builtin_amdgcn_wave_barrier();
    }
}

extern "C" void kernel_launch(void* const* d_in, const int* in_sizes, int n_in,
                              void* d_out, int out_size, void* d_ws, size_t ws_size,
                              hipStream_t stream) {
    const float* x  = (const float*)d_in[0];
    const float* h0 = (const float*)d_in[1];
    const float* c0 = (const float*)d_in[2];
    const float* ih = (const float*)d_in[3];
    const float* hh = (const float*)d_in[4];
    const float* ib = (const float*)d_in[5];
    const float* hb = (const float*)d_in[6];
    float* out = (float*)d_out;

    unsigned short* Wp = (unsigned short*)d_ws;            // 512*256 bf16 = 256 KB
    float* bias = (float*)((char*)d_ws + 512 * 256 * 2);   // 512 f32

    long BH = in_sizes[2];      // B * H
    long B  = BH / HSZ;

    prep_kernel<<<64, 256, 0, stream>>>(ih, hh, ib, hb, Wp, bias);
    lstm_kernel<<<(int)(B / BM), NT, 0, stream>>>(x, h0, c0, Wp, bias, out, BH);
}